// Round 1
// baseline (704.449 us; speedup 1.0000x reference)
//
#include <hip/hip_runtime.h>
#include <hip/hip_bf16.h>
#include <math.h>

// Problem constants (from reference): N=50000 nodes, E=600000 edges, H=128.
#define HD 128
#define NB 16   // nodes per block in GEMM kernels; 50000 % 16 == 0

// ---------------------------------------------------------------------------
// K1: fused encoder + message pre-GEMMs.
//   z = relu([x, pre_h] @ enc_w + enc_b)            (K = 129)
//   P = z @ M_w[0:128]   + M_b                      (K = 128)
//   Q = z @ M_w[128:256]                            (K = 128)
// z written to z_out (lives in d_out's h region, overwritten tile-locally
// later by K4), P/Q to workspace.
// Block: 256 threads = 16 nodes x 128 cols, each thread does 8 nodes x 1 col.
// ---------------------------------------------------------------------------
__global__ __launch_bounds__(256) void k_enc_pq(
    const float* __restrict__ x, const float* __restrict__ pre_h,
    const float* __restrict__ enc_w, const float* __restrict__ enc_b,
    const float* __restrict__ M_w, const float* __restrict__ M_b,
    float* __restrict__ z_out, float* __restrict__ P, float* __restrict__ Q) {
  __shared__ float ph[NB][HD];
  __shared__ float xs[NB];
  __shared__ float zs[NB][HD];
  const int t = threadIdx.x;
  const int n0 = blockIdx.x * NB;

  // cooperative load: 16x128 pre_h row tile + 16 x values
#pragma unroll
  for (int i = 0; i < NB * HD / 256; ++i) {
    int idx = t + i * 256;
    int r = idx >> 7, c = idx & 127;
    ph[r][c] = pre_h[(size_t)(n0 + r) * HD + c];
  }
  if (t < NB) xs[t] = x[n0 + t];
  __syncthreads();

  const int j = t & 127;   // output column
  const int rb = t >> 7;   // 0/1 row base

  // ---- encoder ----
  float acc[8];
  {
    const float w0 = enc_w[j];  // weight row for x (k=0)
    const float b = enc_b[j];
#pragma unroll
    for (int i = 0; i < 8; ++i) acc[i] = b + xs[rb + 2 * i] * w0;
    for (int k = 0; k < HD; k += 4) {
      const float w1 = enc_w[(1 + k) * HD + j];
      const float w2 = enc_w[(2 + k) * HD + j];
      const float w3 = enc_w[(3 + k) * HD + j];
      const float w4 = enc_w[(4 + k) * HD + j];
#pragma unroll
      for (int i = 0; i < 8; ++i) {
        const float4 zv = *(const float4*)&ph[rb + 2 * i][k];
        acc[i] += zv.x * w1 + zv.y * w2 + zv.z * w3 + zv.w * w4;
      }
    }
#pragma unroll
    for (int i = 0; i < 8; ++i) {
      const int r = rb + 2 * i;
      const float zv = fmaxf(acc[i], 0.0f);
      zs[r][j] = zv;
      z_out[(size_t)(n0 + r) * HD + j] = zv;
    }
  }
  __syncthreads();

  // ---- P and Q (share the z LDS broadcast reads) ----
  float accP[8], accQ[8];
  {
    const float bP = M_b[j];
#pragma unroll
    for (int i = 0; i < 8; ++i) { accP[i] = bP; accQ[i] = 0.0f; }
    for (int k = 0; k < HD; k += 4) {
      const float p1 = M_w[(k + 0) * HD + j];
      const float p2 = M_w[(k + 1) * HD + j];
      const float p3 = M_w[(k + 2) * HD + j];
      const float p4 = M_w[(k + 3) * HD + j];
      const float q1 = M_w[(HD + k + 0) * HD + j];
      const float q2 = M_w[(HD + k + 1) * HD + j];
      const float q3 = M_w[(HD + k + 2) * HD + j];
      const float q4 = M_w[(HD + k + 3) * HD + j];
#pragma unroll
      for (int i = 0; i < 8; ++i) {
        const float4 zv = *(const float4*)&zs[rb + 2 * i][k];
        accP[i] += zv.x * p1 + zv.y * p2 + zv.z * p3 + zv.w * p4;
        accQ[i] += zv.x * q1 + zv.y * q2 + zv.z * q3 + zv.w * q4;
      }
    }
#pragma unroll
    for (int i = 0; i < 8; ++i) {
      const int r = rb + 2 * i;
      P[(size_t)(n0 + r) * HD + j] = accP[i];
      Q[(size_t)(n0 + r) * HD + j] = accQ[i];
    }
  }
}

// ---------------------------------------------------------------------------
// K2: edge scatter-max.  One wave (64 lanes) per edge, float2 per lane.
//   v = P[tgt] + Q[src] + attr * M_w[256]   (bias already in P)
//   agg[tgt] = max(agg[tgt], v)  via signed-int atomicMax; agg pre-zeroed,
//   which implements relu+segment_max+empty->0 exactly (values compared are
//   0 or finite floats; positive int order == float order, negatives < 0).
// ---------------------------------------------------------------------------
__global__ __launch_bounds__(256) void k_edge(
    const int* __restrict__ ei, const float* __restrict__ edge_attr,
    const float* __restrict__ P, const float* __restrict__ Q,
    const float* __restrict__ w_attr,  // = M_w + 256*128
    int* __restrict__ agg, int E) {
  const int e = blockIdx.x * 4 + (threadIdx.x >> 6);
  if (e >= E) return;
  const int l = threadIdx.x & 63;
  const int src = ei[e];
  const int tgt = ei[E + e];
  const float a = edge_attr[e];
  const float2 wa = ((const float2*)w_attr)[l];
  const float2 p = ((const float2*)(P + (size_t)tgt * HD))[l];
  const float2 q = ((const float2*)(Q + (size_t)src * HD))[l];
  const float vx = p.x + q.x + a * wa.x;
  const float vy = p.y + q.y + a * wa.y;
  int* base = agg + (size_t)tgt * HD + 2 * l;
  atomicMax(base, __float_as_int(vx));
  atomicMax(base + 1, __float_as_int(vy));
}

// ---------------------------------------------------------------------------
// K3: fused update-GEMM + decoder + h column-sum.
//   h = relu([z, agg] @ U_w + U_b)   -> d_out[0 : N*H]  (overwrites z tile)
//   y = sigmoid([z, h] @ dec_w + dec_b) -> d_out[N*H : N*H+N]
//   hsum[j] += sum over block's nodes of h[n][j]  (for terminator mean)
// ---------------------------------------------------------------------------
__global__ __launch_bounds__(256) void k_update(
    const float* __restrict__ z, const float* __restrict__ agg,
    const float* __restrict__ U_w, const float* __restrict__ U_b,
    const float* __restrict__ dec_w, const float* __restrict__ dec_b,
    float* __restrict__ h_out, float* __restrict__ y_out,
    float* __restrict__ hsum) {
  __shared__ float zsh[NB][HD];
  __shared__ float ash[NB][HD];
  __shared__ float hsh[NB][HD];
  __shared__ float red[256];
  __shared__ float pr[NB][16];
  const int t = threadIdx.x;
  const int n0 = blockIdx.x * NB;

#pragma unroll
  for (int i = 0; i < NB * HD / 256; ++i) {
    int idx = t + i * 256;
    int r = idx >> 7, c = idx & 127;
    zsh[r][c] = z[(size_t)(n0 + r) * HD + c];
    ash[r][c] = agg[(size_t)(n0 + r) * HD + c];
  }
  __syncthreads();

  const int j = t & 127;
  const int rb = t >> 7;
  float acc[8];
  {
    const float b = U_b[j];
#pragma unroll
    for (int i = 0; i < 8; ++i) acc[i] = b;
    for (int k = 0; k < HD; k += 4) {
      const float u1 = U_w[(k + 0) * HD + j];
      const float u2 = U_w[(k + 1) * HD + j];
      const float u3 = U_w[(k + 2) * HD + j];
      const float u4 = U_w[(k + 3) * HD + j];
      const float v1 = U_w[(HD + k + 0) * HD + j];
      const float v2 = U_w[(HD + k + 1) * HD + j];
      const float v3 = U_w[(HD + k + 2) * HD + j];
      const float v4 = U_w[(HD + k + 3) * HD + j];
#pragma unroll
      for (int i = 0; i < 8; ++i) {
        const float4 zv = *(const float4*)&zsh[rb + 2 * i][k];
        const float4 av = *(const float4*)&ash[rb + 2 * i][k];
        acc[i] += zv.x * u1 + zv.y * u2 + zv.z * u3 + zv.w * u4;
        acc[i] += av.x * v1 + av.y * v2 + av.z * v3 + av.w * v4;
      }
    }
  }
  float lsum = 0.0f;
#pragma unroll
  for (int i = 0; i < 8; ++i) {
    const int r = rb + 2 * i;
    const float hv = fmaxf(acc[i], 0.0f);
    hsh[r][j] = hv;
    h_out[(size_t)(n0 + r) * HD + j] = hv;
    lsum += hv;
  }
  red[t] = lsum;
  __syncthreads();
  if (t < 128) atomicAdd(&hsum[j], red[t] + red[t + 128]);

  // decoder: node r = t>>4, 16 threads per node, 8 (z,h) pairs each
  {
    const int r = t >> 4, s = t & 15;
    float part = 0.0f;
#pragma unroll
    for (int c = 0; c < 8; ++c) {
      const int k = s * 8 + c;
      part += zsh[r][k] * dec_w[k] + hsh[r][k] * dec_w[HD + k];
    }
    pr[r][s] = part;
  }
  __syncthreads();
  if (t < NB) {
    float d = dec_b[0];
#pragma unroll
    for (int s = 0; s < 16; ++s) d += pr[t][s];
    y_out[n0 + t] = 1.0f / (1.0f + expf(-d));
  }
}

// ---------------------------------------------------------------------------
// K4: terminator. ter = (hsum/N) . (ter_w[:H] + ter_w[H:]) + ter_b
// ---------------------------------------------------------------------------
__global__ __launch_bounds__(128) void k_ter(
    const float* __restrict__ hsum, const float* __restrict__ ter_w,
    const float* __restrict__ ter_b, float* __restrict__ out, float invN) {
  __shared__ float r2[2];
  const int t = threadIdx.x;  // 128
  float v = (hsum[t] * invN) * (ter_w[t] + ter_w[HD + t]);
#pragma unroll
  for (int o = 32; o > 0; o >>= 1) v += __shfl_down(v, o);
  if ((t & 63) == 0) r2[t >> 6] = v;
  __syncthreads();
  if (t == 0) out[0] = r2[0] + r2[1] + ter_b[0];
}

// ---------------------------------------------------------------------------
extern "C" void kernel_launch(void* const* d_in, const int* in_sizes, int n_in,
                              void* d_out, int out_size, void* d_ws, size_t ws_size,
                              hipStream_t stream) {
  const float* x        = (const float*)d_in[0];
  const float* pre_h    = (const float*)d_in[1];
  const float* edge_attr= (const float*)d_in[2];
  const float* enc_w    = (const float*)d_in[3];
  const float* enc_b    = (const float*)d_in[4];
  const float* M_w      = (const float*)d_in[5];
  const float* M_b      = (const float*)d_in[6];
  const float* U_w      = (const float*)d_in[7];
  const float* U_b      = (const float*)d_in[8];
  const float* dec_w    = (const float*)d_in[9];
  const float* dec_b    = (const float*)d_in[10];
  const float* ter_w    = (const float*)d_in[11];
  const float* ter_b    = (const float*)d_in[12];
  const int*   edge_idx = (const int*)d_in[13];

  const int N = in_sizes[0];      // 50000
  const int E = in_sizes[2];      // 600000
  const size_t NH = (size_t)N * HD;

  float* out = (float*)d_out;
  float* h_out = out;             // [0, N*H)
  float* y_out = out + NH;        // [N*H, N*H+N)
  float* ter_out = out + NH + N;  // scalar

  // workspace layout: P | Q | agg | hsum(128)
  float* P    = (float*)d_ws;
  float* Q    = P + NH;
  float* agg  = Q + NH;
  float* hsum = agg + NH;

  // zero agg + hsum (ws is poisoned 0xAA before every call)
  hipMemsetAsync(agg, 0, (NH + HD) * sizeof(float), stream);

  // z lives in d_out's h region; K3 overwrites it tile-locally.
  float* z = h_out;

  const int gemm_blocks = N / NB;  // 3125
  k_enc_pq<<<gemm_blocks, 256, 0, stream>>>(x, pre_h, enc_w, enc_b, M_w, M_b,
                                            z, P, Q);
  k_edge<<<(E + 3) / 4, 256, 0, stream>>>(edge_idx, edge_attr, P, Q,
                                          M_w + 256 * HD, (int*)agg, E);
  k_update<<<gemm_blocks, 256, 0, stream>>>(z, agg, U_w, U_b, dec_w, dec_b,
                                            h_out, y_out, hsum);
  k_ter<<<1, 128, 0, stream>>>(hsum, ter_w, ter_b, ter_out, 1.0f / (float)N);
}

// Round 2
// 424.267 us; speedup vs baseline: 1.6604x; 1.6604x over previous
//
#include <hip/hip_runtime.h>
#include <hip/hip_bf16.h>
#include <math.h>

// Problem constants (from reference): N=50000 nodes, E=600000 edges, H=128.
#define HD 128
#define NB 16   // nodes per block in GEMM kernels; 50000 % 16 == 0

// ---------------------------------------------------------------------------
// K1: fused encoder + message pre-GEMMs.
//   z = relu([x, pre_h] @ enc_w + enc_b)            (K = 129)
//   P = z @ M_w[0:128]   + M_b                      (K = 128)
//   Q = z @ M_w[128:256]                            (K = 128)
// ---------------------------------------------------------------------------
__global__ __launch_bounds__(256) void k_enc_pq(
    const float* __restrict__ x, const float* __restrict__ pre_h,
    const float* __restrict__ enc_w, const float* __restrict__ enc_b,
    const float* __restrict__ M_w, const float* __restrict__ M_b,
    float* __restrict__ z_out, float* __restrict__ P, float* __restrict__ Q) {
  __shared__ float ph[NB][HD];
  __shared__ float xs[NB];
  __shared__ float zs[NB][HD];
  const int t = threadIdx.x;
  const int n0 = blockIdx.x * NB;

#pragma unroll
  for (int i = 0; i < NB * HD / 256; ++i) {
    int idx = t + i * 256;
    int r = idx >> 7, c = idx & 127;
    ph[r][c] = pre_h[(size_t)(n0 + r) * HD + c];
  }
  if (t < NB) xs[t] = x[n0 + t];
  __syncthreads();

  const int j = t & 127;   // output column
  const int rb = t >> 7;   // 0/1 row base

  // ---- encoder ----
  float acc[8];
  {
    const float w0 = enc_w[j];  // weight row for x (k=0)
    const float b = enc_b[j];
#pragma unroll
    for (int i = 0; i < 8; ++i) acc[i] = b + xs[rb + 2 * i] * w0;
    for (int k = 0; k < HD; k += 4) {
      const float w1 = enc_w[(1 + k) * HD + j];
      const float w2 = enc_w[(2 + k) * HD + j];
      const float w3 = enc_w[(3 + k) * HD + j];
      const float w4 = enc_w[(4 + k) * HD + j];
#pragma unroll
      for (int i = 0; i < 8; ++i) {
        const float4 zv = *(const float4*)&ph[rb + 2 * i][k];
        acc[i] += zv.x * w1 + zv.y * w2 + zv.z * w3 + zv.w * w4;
      }
    }
#pragma unroll
    for (int i = 0; i < 8; ++i) {
      const int r = rb + 2 * i;
      const float zv = fmaxf(acc[i], 0.0f);
      zs[r][j] = zv;
      z_out[(size_t)(n0 + r) * HD + j] = zv;
    }
  }
  __syncthreads();

  // ---- P and Q (share the z LDS broadcast reads) ----
  float accP[8], accQ[8];
  {
    const float bP = M_b[j];
#pragma unroll
    for (int i = 0; i < 8; ++i) { accP[i] = bP; accQ[i] = 0.0f; }
    for (int k = 0; k < HD; k += 4) {
      const float p1 = M_w[(k + 0) * HD + j];
      const float p2 = M_w[(k + 1) * HD + j];
      const float p3 = M_w[(k + 2) * HD + j];
      const float p4 = M_w[(k + 3) * HD + j];
      const float q1 = M_w[(HD + k + 0) * HD + j];
      const float q2 = M_w[(HD + k + 1) * HD + j];
      const float q3 = M_w[(HD + k + 2) * HD + j];
      const float q4 = M_w[(HD + k + 3) * HD + j];
#pragma unroll
      for (int i = 0; i < 8; ++i) {
        const float4 zv = *(const float4*)&zs[rb + 2 * i][k];
        accP[i] += zv.x * p1 + zv.y * p2 + zv.z * p3 + zv.w * p4;
        accQ[i] += zv.x * q1 + zv.y * q2 + zv.z * q3 + zv.w * q4;
      }
    }
#pragma unroll
    for (int i = 0; i < 8; ++i) {
      const int r = rb + 2 * i;
      P[(size_t)(n0 + r) * HD + j] = accP[i];
      Q[(size_t)(n0 + r) * HD + j] = accQ[i];
    }
  }
}

// ---------------------------------------------------------------------------
// CSR build: histogram (by target), 3-kernel exclusive scan, scatter.
// ---------------------------------------------------------------------------
__global__ __launch_bounds__(256) void k_hist(
    const int* __restrict__ ei, int* __restrict__ cnt, int E) {
  const int e = blockIdx.x * 256 + threadIdx.x;
  if (e < E) atomicAdd(&cnt[ei[E + e]], 1);
}

// per-block exclusive scan of 1024-element chunks; partials[b] = chunk total
__global__ __launch_bounds__(256) void k_scan_block(
    const int* __restrict__ cnt, int* __restrict__ row_ptr,
    int* __restrict__ partials, int N) {
  __shared__ int s[256];
  const int t = threadIdx.x;
  const int base = blockIdx.x * 1024 + t * 4;
  int v[4], sum = 0;
#pragma unroll
  for (int i = 0; i < 4; ++i) {
    v[i] = (base + i < N) ? cnt[base + i] : 0;
    sum += v[i];
  }
  s[t] = sum;
  __syncthreads();
  for (int off = 1; off < 256; off <<= 1) {
    int xv = (t >= off) ? s[t - off] : 0;
    __syncthreads();
    if (t >= off) s[t] += xv;
    __syncthreads();
  }
  int run = s[t] - sum;  // thread-exclusive prefix within block
  if (t == 255) partials[blockIdx.x] = s[255];
#pragma unroll
  for (int i = 0; i < 4; ++i) {
    if (base + i < N) row_ptr[base + i] = run;
    run += v[i];
  }
}

__global__ void k_scan_partials(int* __restrict__ partials, int nb) {
  if (threadIdx.x == 0) {
    int run = 0;
    for (int i = 0; i < nb; ++i) {
      int v = partials[i];
      partials[i] = run;
      run += v;
    }
  }
}

__global__ __launch_bounds__(256) void k_scan_add(
    int* __restrict__ row_ptr, const int* __restrict__ partials,
    int* __restrict__ cursor, int N) {
  const int base = blockIdx.x * 1024 + threadIdx.x * 4;
  const int p = partials[blockIdx.x];
#pragma unroll
  for (int i = 0; i < 4; ++i) {
    if (base + i < N) {
      int v = row_ptr[base + i] + p;
      row_ptr[base + i] = v;
      cursor[base + i] = v;
    }
  }
}

// scatter packed (src, attr_bits) into CSR buckets (order within bucket is
// irrelevant for max). After this, cursor[n] == row end of node n.
__global__ __launch_bounds__(256) void k_scatter(
    const int* __restrict__ ei, const float* __restrict__ edge_attr,
    int* __restrict__ cursor, int2* __restrict__ epack, int E) {
  const int e = blockIdx.x * 256 + threadIdx.x;
  if (e >= E) return;
  const int tgt = ei[E + e];
  const int pos = atomicAdd(&cursor[tgt], 1);
  epack[pos] = make_int2(ei[e], __float_as_int(edge_attr[e]));
}

// ---------------------------------------------------------------------------
// K3: fused gather-max + update-GEMM + decoder + h column-sum.
//   agg[n] = relu(P[n] + max_{e in csr(n)} (Q[src_e] + attr_e*w_attr)),
//            empty -> 0   (computed into LDS, never materialized)
//   h = relu([z, agg] @ U_w + U_b)   -> d_out[0 : N*H]
//   y = sigmoid([z, h] @ dec_w + dec_b) -> d_out[N*H : ...]
//   hsum[j] += per-block column sums of h (for terminator mean)
// ---------------------------------------------------------------------------
__global__ __launch_bounds__(256) void k_update(
    const float* __restrict__ z, const float* __restrict__ P,
    const float* __restrict__ Q, const float* __restrict__ w_attr,
    const int* __restrict__ row_ptr, const int* __restrict__ row_end,
    const int2* __restrict__ epack,
    const float* __restrict__ U_w, const float* __restrict__ U_b,
    const float* __restrict__ dec_w, const float* __restrict__ dec_b,
    float* __restrict__ h_out, float* __restrict__ y_out,
    float* __restrict__ hsum) {
  __shared__ float zsh[NB][HD];
  __shared__ float ash[NB][HD];
  __shared__ float hsh[NB][HD];
  __shared__ float red[256];
  __shared__ float pr[NB][16];
  const int t = threadIdx.x;
  const int n0 = blockIdx.x * NB;

#pragma unroll
  for (int i = 0; i < NB * HD / 256; ++i) {
    int idx = t + i * 256;
    int r = idx >> 7, c = idx & 127;
    zsh[r][c] = z[(size_t)(n0 + r) * HD + c];
  }

  // ---- gather-max: wave w handles nodes w*4 .. w*4+3, float2 per lane ----
  {
    const int w = t >> 6, l = t & 63;
    const float2 wa = ((const float2*)w_attr)[l];
#pragma unroll
    for (int i = 0; i < 4; ++i) {
      const int r = w * 4 + i;
      const int n = n0 + r;
      const int rs = row_ptr[n];
      const int re = row_end[n];
      float2 acc = make_float2(-INFINITY, -INFINITY);
      int e = rs;
      for (; e + 1 < re; e += 2) {
        const int2 p0 = epack[e];
        const int2 p1 = epack[e + 1];
        const float2 q0 = ((const float2*)(Q + (size_t)p0.x * HD))[l];
        const float2 q1 = ((const float2*)(Q + (size_t)p1.x * HD))[l];
        const float a0 = __int_as_float(p0.y);
        const float a1 = __int_as_float(p1.y);
        acc.x = fmaxf(acc.x, fmaxf(q0.x + a0 * wa.x, q1.x + a1 * wa.x));
        acc.y = fmaxf(acc.y, fmaxf(q0.y + a0 * wa.y, q1.y + a1 * wa.y));
      }
      if (e < re) {
        const int2 p0 = epack[e];
        const float2 q0 = ((const float2*)(Q + (size_t)p0.x * HD))[l];
        const float a0 = __int_as_float(p0.y);
        acc.x = fmaxf(acc.x, q0.x + a0 * wa.x);
        acc.y = fmaxf(acc.y, q0.y + a0 * wa.y);
      }
      float2 res;
      if (re > rs) {
        const float2 pv = ((const float2*)(P + (size_t)n * HD))[l];
        res.x = fmaxf(pv.x + acc.x, 0.0f);
        res.y = fmaxf(pv.y + acc.y, 0.0f);
      } else {
        res = make_float2(0.0f, 0.0f);
      }
      *(float2*)&ash[r][2 * l] = res;
    }
  }
  __syncthreads();

  const int j = t & 127;
  const int rb = t >> 7;
  float acc[8];
  {
    const float b = U_b[j];
#pragma unroll
    for (int i = 0; i < 8; ++i) acc[i] = b;
    for (int k = 0; k < HD; k += 4) {
      const float u1 = U_w[(k + 0) * HD + j];
      const float u2 = U_w[(k + 1) * HD + j];
      const float u3 = U_w[(k + 2) * HD + j];
      const float u4 = U_w[(k + 3) * HD + j];
      const float v1 = U_w[(HD + k + 0) * HD + j];
      const float v2 = U_w[(HD + k + 1) * HD + j];
      const float v3 = U_w[(HD + k + 2) * HD + j];
      const float v4 = U_w[(HD + k + 3) * HD + j];
#pragma unroll
      for (int i = 0; i < 8; ++i) {
        const float4 zv = *(const float4*)&zsh[rb + 2 * i][k];
        const float4 av = *(const float4*)&ash[rb + 2 * i][k];
        acc[i] += zv.x * u1 + zv.y * u2 + zv.z * u3 + zv.w * u4;
        acc[i] += av.x * v1 + av.y * v2 + av.z * v3 + av.w * v4;
      }
    }
  }
  float lsum = 0.0f;
#pragma unroll
  for (int i = 0; i < 8; ++i) {
    const int r = rb + 2 * i;
    const float hv = fmaxf(acc[i], 0.0f);
    hsh[r][j] = hv;
    h_out[(size_t)(n0 + r) * HD + j] = hv;
    lsum += hv;
  }
  red[t] = lsum;
  __syncthreads();
  if (t < 128) atomicAdd(&hsum[j], red[t] + red[t + 128]);

  // decoder: node r = t>>4, 16 threads per node, 8 (z,h) pairs each
  {
    const int r = t >> 4, s = t & 15;
    float part = 0.0f;
#pragma unroll
    for (int c = 0; c < 8; ++c) {
      const int k = s * 8 + c;
      part += zsh[r][k] * dec_w[k] + hsh[r][k] * dec_w[HD + k];
    }
    pr[r][s] = part;
  }
  __syncthreads();
  if (t < NB) {
    float d = dec_b[0];
#pragma unroll
    for (int s = 0; s < 16; ++s) d += pr[t][s];
    y_out[n0 + t] = 1.0f / (1.0f + expf(-d));
  }
}

// ---------------------------------------------------------------------------
// K4: terminator. ter = (hsum/N) . (ter_w[:H] + ter_w[H:]) + ter_b
// ---------------------------------------------------------------------------
__global__ __launch_bounds__(128) void k_ter(
    const float* __restrict__ hsum, const float* __restrict__ ter_w,
    const float* __restrict__ ter_b, float* __restrict__ out, float invN) {
  __shared__ float r2[2];
  const int t = threadIdx.x;  // 128
  float v = (hsum[t] * invN) * (ter_w[t] + ter_w[HD + t]);
#pragma unroll
  for (int o = 32; o > 0; o >>= 1) v += __shfl_down(v, o);
  if ((t & 63) == 0) r2[t >> 6] = v;
  __syncthreads();
  if (t == 0) out[0] = r2[0] + r2[1] + ter_b[0];
}

// ---------------------------------------------------------------------------
extern "C" void kernel_launch(void* const* d_in, const int* in_sizes, int n_in,
                              void* d_out, int out_size, void* d_ws, size_t ws_size,
                              hipStream_t stream) {
  const float* x        = (const float*)d_in[0];
  const float* pre_h    = (const float*)d_in[1];
  const float* edge_attr= (const float*)d_in[2];
  const float* enc_w    = (const float*)d_in[3];
  const float* enc_b    = (const float*)d_in[4];
  const float* M_w      = (const float*)d_in[5];
  const float* M_b      = (const float*)d_in[6];
  const float* U_w      = (const float*)d_in[7];
  const float* U_b      = (const float*)d_in[8];
  const float* dec_w    = (const float*)d_in[9];
  const float* dec_b    = (const float*)d_in[10];
  const float* ter_w    = (const float*)d_in[11];
  const float* ter_b    = (const float*)d_in[12];
  const int*   edge_idx = (const int*)d_in[13];

  const int N = in_sizes[0];      // 50000
  const int E = in_sizes[2];      // 600000
  const size_t NH = (size_t)N * HD;

  float* out = (float*)d_out;
  float* h_out = out;             // [0, N*H)
  float* y_out = out + NH;        // [N*H, N*H+N)
  float* ter_out = out + NH + N;  // scalar

  // workspace layout: P | Q | cursor(N) | row_ptr(N) | partials(64) | hsum(128) | epack(E int2)
  float* P       = (float*)d_ws;
  float* Q       = P + NH;
  int*   cursor  = (int*)(Q + NH);
  int*   row_ptr = cursor + N;
  int*   partials= row_ptr + N;
  float* hsum    = (float*)(partials + 64);
  int2*  epack   = (int2*)(hsum + HD);

  // zero cursor..hsum in one shot (covers cnt histogram init + hsum)
  hipMemsetAsync(cursor, 0, (2 * (size_t)N + 64 + HD) * sizeof(int), stream);

  const int scan_blocks = (N + 1023) / 1024;  // 49
  const int eb = (E + 255) / 256;             // 2344

  // CSR build (independent of GEMMs)
  k_hist<<<eb, 256, 0, stream>>>(edge_idx, cursor, E);
  k_scan_block<<<scan_blocks, 256, 0, stream>>>(cursor, row_ptr, partials, N);
  k_scan_partials<<<1, 64, 0, stream>>>(partials, scan_blocks);
  k_scan_add<<<scan_blocks, 256, 0, stream>>>(row_ptr, partials, cursor, N);
  k_scatter<<<eb, 256, 0, stream>>>(edge_idx, edge_attr, cursor, epack, E);

  // z lives in d_out's h region; k_update overwrites it tile-locally.
  float* z = h_out;
  const int gemm_blocks = N / NB;  // 3125
  k_enc_pq<<<gemm_blocks, 256, 0, stream>>>(x, pre_h, enc_w, enc_b, M_w, M_b,
                                            z, P, Q);
  k_update<<<gemm_blocks, 256, 0, stream>>>(z, P, Q, M_w + 256 * HD,
                                            row_ptr, cursor, epack,
                                            U_w, U_b, dec_w, dec_b,
                                            h_out, y_out, hsum);
  k_ter<<<1, 128, 0, stream>>>(hsum, ter_w, ter_b, ter_out, 1.0f / (float)N);
}

// Round 3
// 276.863 us; speedup vs baseline: 2.5444x; 1.5324x over previous
//
#include <hip/hip_runtime.h>
#include <hip/hip_bf16.h>
#include <math.h>

// N=50000 nodes, E=600000 edges, H=128.
#define HD 128
#define APAD 136   // LDS row stride in ushorts (+8 pad: 272 B rows, 16B-aligned, 2-way bank alias = free)
#define CAP 1024   // staged edges per block (mean ~384, sigma ~20; global fallback beyond)

typedef short bf16x8 __attribute__((ext_vector_type(8)));
typedef float f32x4 __attribute__((ext_vector_type(4)));

static __device__ __forceinline__ unsigned short f2bf(float f) {
  __hip_bfloat16 b = __float2bfloat16(f);
  return *(unsigned short*)&b;
}
static __device__ __forceinline__ float bflo(unsigned int u) {
  return __uint_as_float(u << 16);
}
static __device__ __forceinline__ float bfhi(unsigned int u) {
  return __uint_as_float(u & 0xffff0000u);
}

// ---------------------------------------------------------------------------
// K0: pack weights into MFMA B-fragment order, bf16.
// F[((tile*KS+ks)*64+lane)*8+j] = bf16(W[(ks*32+(lane>>4)*8+j)*128 + tile*16+(lane&15)])
// blocks 0-7: encf (enc_w rows 1..128), 8-15: Pf (M_w rows 0..127),
// 16-23: Qf (M_w rows 128..255), 24-39: Uf (U_w, K=256).
// ---------------------------------------------------------------------------
__global__ __launch_bounds__(256) void k_frag(
    const float* __restrict__ enc_w, const float* __restrict__ M_w,
    const float* __restrict__ U_w,
    unsigned short* __restrict__ encf, unsigned short* __restrict__ Pf,
    unsigned short* __restrict__ Qf, unsigned short* __restrict__ Uf) {
  const int b = blockIdx.x;
  const float* W; unsigned short* F; int KS; int lb;
  if (b < 8)       { W = enc_w + HD;     F = encf; KS = 4; lb = b; }
  else if (b < 16) { W = M_w;            F = Pf;   KS = 4; lb = b - 8; }
  else if (b < 24) { W = M_w + HD * HD;  F = Qf;   KS = 4; lb = b - 16; }
  else             { W = U_w;            F = Uf;   KS = 8; lb = b - 24; }
  const int gid = lb * 256 + threadIdx.x;
  const int lane = gid & 63;
  const int ks = (gid >> 6) % KS;
  const int tile = gid / (64 * KS);
  const int col = tile * 16 + (lane & 15);
  const int k0 = ks * 32 + (lane >> 4) * 8;
  unsigned short v[8];
#pragma unroll
  for (int j = 0; j < 8; ++j) v[j] = f2bf(W[(size_t)(k0 + j) * HD + col]);
  unsigned short* dst = F + ((size_t)(tile * KS + ks) * 64 + lane) * 8;
#pragma unroll
  for (int j = 0; j < 8; ++j) dst[j] = v[j];
}

// ---------------------------------------------------------------------------
// CSR build (unchanged from round 2).
// ---------------------------------------------------------------------------
__global__ __launch_bounds__(256) void k_hist(
    const int* __restrict__ ei, int* __restrict__ cnt, int E) {
  const int e = blockIdx.x * 256 + threadIdx.x;
  if (e < E) atomicAdd(&cnt[ei[E + e]], 1);
}

__global__ __launch_bounds__(256) void k_scan_block(
    const int* __restrict__ cnt, int* __restrict__ row_ptr,
    int* __restrict__ partials, int N) {
  __shared__ int s[256];
  const int t = threadIdx.x;
  const int base = blockIdx.x * 1024 + t * 4;
  int v[4], sum = 0;
#pragma unroll
  for (int i = 0; i < 4; ++i) {
    v[i] = (base + i < N) ? cnt[base + i] : 0;
    sum += v[i];
  }
  s[t] = sum;
  __syncthreads();
  for (int off = 1; off < 256; off <<= 1) {
    int xv = (t >= off) ? s[t - off] : 0;
    __syncthreads();
    if (t >= off) s[t] += xv;
    __syncthreads();
  }
  int run = s[t] - sum;
  if (t == 255) partials[blockIdx.x] = s[255];
#pragma unroll
  for (int i = 0; i < 4; ++i) {
    if (base + i < N) row_ptr[base + i] = run;
    run += v[i];
  }
}

__global__ void k_scan_partials(int* __restrict__ partials, int nb) {
  if (threadIdx.x == 0) {
    int run = 0;
    for (int i = 0; i < nb; ++i) { int v = partials[i]; partials[i] = run; run += v; }
  }
}

__global__ __launch_bounds__(256) void k_scan_add(
    int* __restrict__ row_ptr, const int* __restrict__ partials,
    int* __restrict__ cursor, int N) {
  const int base = blockIdx.x * 1024 + threadIdx.x * 4;
  const int p = partials[blockIdx.x];
#pragma unroll
  for (int i = 0; i < 4; ++i) {
    if (base + i < N) {
      int v = row_ptr[base + i] + p;
      row_ptr[base + i] = v;
      cursor[base + i] = v;
    }
  }
}

__global__ __launch_bounds__(256) void k_scatter(
    const int* __restrict__ ei, const float* __restrict__ edge_attr,
    int* __restrict__ cursor, int2* __restrict__ epack, int E) {
  const int e = blockIdx.x * 256 + threadIdx.x;
  if (e >= E) return;
  const int tgt = ei[E + e];
  const int pos = atomicAdd(&cursor[tgt], 1);
  epack[pos] = make_int2(ei[e], __float_as_int(edge_attr[e]));
}

// ---------------------------------------------------------------------------
// K1: MFMA encoder + P/Q.  16 nodes/block, 256 thr = 4 waves.
// Wave w computes cols [32w, 32w+32) (2 N-tiles), all 16 rows.
//   z = relu(pre_h @ enc_w[1:] + x (x) enc_w[0] + enc_b)  -> zg (bf16)
//   P = z @ M_w[0:128] + M_b -> Pg (bf16);  Q = z @ M_w[128:256] -> Qg (bf16)
// ---------------------------------------------------------------------------
__global__ __launch_bounds__(256, 4) void k_enc_pq(
    const float* __restrict__ x, const float* __restrict__ pre_h,
    const float* __restrict__ enc_w, const float* __restrict__ enc_b,
    const float* __restrict__ M_b,
    const unsigned short* __restrict__ encf, const unsigned short* __restrict__ Pf,
    const unsigned short* __restrict__ Qf,
    unsigned short* __restrict__ zg, unsigned short* __restrict__ Pg,
    unsigned short* __restrict__ Qg) {
  __shared__ unsigned short phs[16 * APAD];  // pre_h bf16; later P staging
  __shared__ unsigned short zsh[16 * APAD];  // z bf16; later Q staging
  __shared__ float xs[16];
  const int t = threadIdx.x;
  const int n0 = blockIdx.x * 16;

  // stage pre_h -> bf16 LDS (8 floats/thread)
  {
    const int r = t >> 4, c0 = (t & 15) * 8;
    const float4 a = *(const float4*)&pre_h[(size_t)(n0 + r) * HD + c0];
    const float4 b = *(const float4*)&pre_h[(size_t)(n0 + r) * HD + c0 + 4];
    unsigned short* d = &phs[r * APAD + c0];
    d[0] = f2bf(a.x); d[1] = f2bf(a.y); d[2] = f2bf(a.z); d[3] = f2bf(a.w);
    d[4] = f2bf(b.x); d[5] = f2bf(b.y); d[6] = f2bf(b.z); d[7] = f2bf(b.w);
  }
  if (t < 16) xs[t] = x[n0 + t];
  __syncthreads();

  const int w = t >> 6, l = t & 63;
  const int m = l & 15, q = l >> 4;

  // ---- encoder MFMA ----
  bf16x8 af[4];
#pragma unroll
  for (int ks = 0; ks < 4; ++ks)
    af[ks] = *(const bf16x8*)&phs[m * APAD + ks * 32 + q * 8];
  f32x4 acc[2] = {{0, 0, 0, 0}, {0, 0, 0, 0}};
#pragma unroll
  for (int tt = 0; tt < 2; ++tt) {
    const int tn = 2 * w + tt;
#pragma unroll
    for (int ks = 0; ks < 4; ++ks) {
      const bf16x8 bf = *(const bf16x8*)&encf[((size_t)(tn * 4 + ks) * 64 + l) * 8];
      acc[tt] = __builtin_amdgcn_mfma_f32_16x16x32_bf16(af[ks], bf, acc[tt], 0, 0, 0);
    }
  }
#pragma unroll
  for (int tt = 0; tt < 2; ++tt) {
    const int col = (2 * w + tt) * 16 + m;
    const float bb = enc_b[col];
    const float w0 = enc_w[col];  // row 0 (x feature)
#pragma unroll
    for (int r = 0; r < 4; ++r) {
      const int row = q * 4 + r;
      const float zv = fmaxf(acc[tt][r] + bb + xs[row] * w0, 0.0f);
      zsh[row * APAD + col] = f2bf(zv);
    }
  }
  __syncthreads();

  // A-frags from z; coalesced zg store
  bf16x8 az[4];
#pragma unroll
  for (int ks = 0; ks < 4; ++ks)
    az[ks] = *(const bf16x8*)&zsh[m * APAD + ks * 32 + q * 8];
  {
    const int r = t >> 4, c0 = (t & 15) * 8;
    *(uint4*)&zg[(size_t)(n0 + r) * HD + c0] = *(const uint4*)&zsh[r * APAD + c0];
  }
  __syncthreads();

  // ---- P/Q MFMA ----
  f32x4 pacc[2] = {{0, 0, 0, 0}, {0, 0, 0, 0}};
  f32x4 qacc[2] = {{0, 0, 0, 0}, {0, 0, 0, 0}};
#pragma unroll
  for (int tt = 0; tt < 2; ++tt) {
    const int tn = 2 * w + tt;
#pragma unroll
    for (int ks = 0; ks < 4; ++ks) {
      const bf16x8 bp = *(const bf16x8*)&Pf[((size_t)(tn * 4 + ks) * 64 + l) * 8];
      const bf16x8 bq = *(const bf16x8*)&Qf[((size_t)(tn * 4 + ks) * 64 + l) * 8];
      pacc[tt] = __builtin_amdgcn_mfma_f32_16x16x32_bf16(az[ks], bp, pacc[tt], 0, 0, 0);
      qacc[tt] = __builtin_amdgcn_mfma_f32_16x16x32_bf16(az[ks], bq, qacc[tt], 0, 0, 0);
    }
  }
#pragma unroll
  for (int tt = 0; tt < 2; ++tt) {
    const int col = (2 * w + tt) * 16 + m;
    const float mb = M_b[col];
#pragma unroll
    for (int r = 0; r < 4; ++r) {
      const int row = q * 4 + r;
      phs[row * APAD + col] = f2bf(pacc[tt][r] + mb);  // P staging (bias folded)
      zsh[row * APAD + col] = f2bf(qacc[tt][r]);       // Q staging
    }
  }
  __syncthreads();
  {
    const int r = t >> 4, c0 = (t & 15) * 8;
    *(uint4*)&Pg[(size_t)(n0 + r) * HD + c0] = *(const uint4*)&phs[r * APAD + c0];
    *(uint4*)&Qg[(size_t)(n0 + r) * HD + c0] = *(const uint4*)&zsh[r * APAD + c0];
  }
}

// ---------------------------------------------------------------------------
// K2: gather-max + U-GEMM (MFMA) + decoder + h column sums.
// 32 nodes/block, 256 thr = 4 waves.  Guarded for N not divisible by 32.
// ---------------------------------------------------------------------------
__global__ __launch_bounds__(256, 4) void k_gather_update(
    const unsigned short* __restrict__ zg, const unsigned short* __restrict__ Pg,
    const unsigned short* __restrict__ Qg, const float* __restrict__ w_attr,
    const int* __restrict__ row_ptr, const int* __restrict__ row_end,
    const int2* __restrict__ epack, const unsigned short* __restrict__ Uf,
    const float* __restrict__ U_b, const float* __restrict__ dec_w,
    const float* __restrict__ dec_b,
    float* __restrict__ h_out, float* __restrict__ y_out,
    float* __restrict__ hsum, int N) {
  __shared__ unsigned short zsh[32 * APAD];
  __shared__ unsigned short ash[32 * APAD];
  __shared__ unsigned short hsh[32 * APAD];
  __shared__ int2 eL[CAP];
  __shared__ int rsL[32], reL[32];
  __shared__ float hcol[HD];
  __shared__ float pr[32][8];
  const int t = threadIdx.x;
  const int n0 = blockIdx.x * 32;

  // stage z tile (clamped), row ptrs, zero hcol
  {
    const int r = t >> 3, c0 = (t & 7) * 16;
    const int n = min(n0 + r, N - 1);
    *(uint4*)&zsh[r * APAD + c0]     = *(const uint4*)&zg[(size_t)n * HD + c0];
    *(uint4*)&zsh[r * APAD + c0 + 8] = *(const uint4*)&zg[(size_t)n * HD + c0 + 8];
  }
  if (t < 32) {
    const int n = min(n0 + t, N - 1);
    rsL[t] = row_ptr[n];
    reL[t] = row_end[n];
  }
  if (t < HD) hcol[t] = 0.0f;
  __syncthreads();
  const int estart = rsL[0];
  const int ecnt = reL[31] - estart;
  for (int i = t; i < min(ecnt, CAP); i += 256) eL[i] = epack[estart + i];
  __syncthreads();

  const int w = t >> 6, l = t & 63;
  const float2 wav = ((const float2*)w_attr)[l];

  // ---- gather-max: wave w -> nodes w*8 .. w*8+7, 2 cols/lane ----
  for (int i = 0; i < 8; ++i) {
    const int r = w * 8 + i;
    const int n = n0 + r;
    const int rs = rsL[r], re = reL[r];
    const bool valid = (n < N) && (re > rs);
    float2 acc = make_float2(-INFINITY, -INFINITY);
    int e = rs;
    for (; e + 3 < re; e += 4) {
      const int i0 = e - estart;
      const int2 pk0 = (i0 + 0 < CAP) ? eL[i0 + 0] : epack[e + 0];
      const int2 pk1 = (i0 + 1 < CAP) ? eL[i0 + 1] : epack[e + 1];
      const int2 pk2 = (i0 + 2 < CAP) ? eL[i0 + 2] : epack[e + 2];
      const int2 pk3 = (i0 + 3 < CAP) ? eL[i0 + 3] : epack[e + 3];
      const unsigned int q0 = *(const unsigned int*)&Qg[(size_t)pk0.x * HD + 2 * l];
      const unsigned int q1 = *(const unsigned int*)&Qg[(size_t)pk1.x * HD + 2 * l];
      const unsigned int q2 = *(const unsigned int*)&Qg[(size_t)pk2.x * HD + 2 * l];
      const unsigned int q3 = *(const unsigned int*)&Qg[(size_t)pk3.x * HD + 2 * l];
      const float a0 = __int_as_float(pk0.y), a1 = __int_as_float(pk1.y);
      const float a2 = __int_as_float(pk2.y), a3 = __int_as_float(pk3.y);
      acc.x = fmaxf(acc.x, fmaxf(fmaxf(bflo(q0) + a0 * wav.x, bflo(q1) + a1 * wav.x),
                                 fmaxf(bflo(q2) + a2 * wav.x, bflo(q3) + a3 * wav.x)));
      acc.y = fmaxf(acc.y, fmaxf(fmaxf(bfhi(q0) + a0 * wav.y, bfhi(q1) + a1 * wav.y),
                                 fmaxf(bfhi(q2) + a2 * wav.y, bfhi(q3) + a3 * wav.y)));
    }
    for (; e < re; ++e) {
      const int i0 = e - estart;
      const int2 pk = (i0 < CAP) ? eL[i0] : epack[e];
      const unsigned int qv = *(const unsigned int*)&Qg[(size_t)pk.x * HD + 2 * l];
      const float a = __int_as_float(pk.y);
      acc.x = fmaxf(acc.x, bflo(qv) + a * wav.x);
      acc.y = fmaxf(acc.y, bfhi(qv) + a * wav.y);
    }
    float2 res = make_float2(0.0f, 0.0f);
    if (valid) {
      const unsigned int pv = *(const unsigned int*)&Pg[(size_t)n * HD + 2 * l];
      res.x = fmaxf(bflo(pv) + acc.x, 0.0f);
      res.y = fmaxf(bfhi(pv) + acc.y, 0.0f);
    }
    const unsigned int packed = (unsigned int)f2bf(res.x) | ((unsigned int)f2bf(res.y) << 16);
    *(unsigned int*)&ash[r * APAD + 2 * l] = packed;
  }
  __syncthreads();

  // ---- U-GEMM: wave w -> M-tile (w&1), cols [64*(w>>1), +64) ----
  const int mt = w & 1, nh = w >> 1;
  const int m = mt * 16 + (l & 15), q = l >> 4;
  bf16x8 afz[4], afa[4];
#pragma unroll
  for (int ks = 0; ks < 4; ++ks) {
    afz[ks] = *(const bf16x8*)&zsh[m * APAD + ks * 32 + q * 8];
    afa[ks] = *(const bf16x8*)&ash[m * APAD + ks * 32 + q * 8];
  }
  f32x4 acc4[4] = {{0, 0, 0, 0}, {0, 0, 0, 0}, {0, 0, 0, 0}, {0, 0, 0, 0}};
#pragma unroll
  for (int tt = 0; tt < 4; ++tt) {
    const int tn = nh * 4 + tt;
#pragma unroll
    for (int ks = 0; ks < 8; ++ks) {
      const bf16x8 bf = *(const bf16x8*)&Uf[((size_t)(tn * 8 + ks) * 64 + l) * 8];
      const bf16x8 a = (ks < 4) ? afz[ks] : afa[ks - 4];
      acc4[tt] = __builtin_amdgcn_mfma_f32_16x16x32_bf16(a, bf, acc4[tt], 0, 0, 0);
    }
  }
#pragma unroll
  for (int tt = 0; tt < 4; ++tt) {
    const int col = (nh * 4 + tt) * 16 + (l & 15);
    const float ub = U_b[col];
    float s4 = 0.0f;
#pragma unroll
    for (int r = 0; r < 4; ++r) {
      const int rowl = mt * 16 + q * 4 + r;
      const int n = n0 + rowl;
      float hv = fmaxf(acc4[tt][r] + ub, 0.0f);
      if (n < N) h_out[(size_t)n * HD + col] = hv; else hv = 0.0f;
      hsh[rowl * APAD + col] = f2bf(hv);
      s4 += hv;
    }
    atomicAdd(&hcol[col], s4);
  }
  __syncthreads();

  if (t < HD) atomicAdd(&hsum[t], hcol[t]);

  // ---- decoder: thread t -> node t>>3, cols (t&7)*16 .. +15 ----
  {
    const int r2 = t >> 3, s = t & 7;
    float part = 0.0f;
#pragma unroll
    for (int c = 0; c < 8; ++c) {
      const int kk = s * 16 + 2 * c;
      const unsigned int zu = *(const unsigned int*)&zsh[r2 * APAD + kk];
      const unsigned int hu = *(const unsigned int*)&hsh[r2 * APAD + kk];
      part += bflo(zu) * dec_w[kk] + bfhi(zu) * dec_w[kk + 1];
      part += bflo(hu) * dec_w[HD + kk] + bfhi(hu) * dec_w[HD + kk + 1];
    }
    pr[r2][s] = part;
  }
  __syncthreads();
  if (t < 32 && n0 + t < N) {
    float d = dec_b[0];
#pragma unroll
    for (int s = 0; s < 8; ++s) d += pr[t][s];
    y_out[n0 + t] = 1.0f / (1.0f + expf(-d));
  }
}

// ---------------------------------------------------------------------------
// K3: terminator. ter = (hsum/N) . (ter_w[:H] + ter_w[H:]) + ter_b
// ---------------------------------------------------------------------------
__global__ __launch_bounds__(128) void k_ter(
    const float* __restrict__ hsum, const float* __restrict__ ter_w,
    const float* __restrict__ ter_b, float* __restrict__ out, float invN) {
  __shared__ float r2[2];
  const int t = threadIdx.x;
  float v = (hsum[t] * invN) * (ter_w[t] + ter_w[HD + t]);
#pragma unroll
  for (int o = 32; o > 0; o >>= 1) v += __shfl_down(v, o);
  if ((t & 63) == 0) r2[t >> 6] = v;
  __syncthreads();
  if (t == 0) out[0] = r2[0] + r2[1] + ter_b[0];
}

// ---------------------------------------------------------------------------
extern "C" void kernel_launch(void* const* d_in, const int* in_sizes, int n_in,
                              void* d_out, int out_size, void* d_ws, size_t ws_size,
                              hipStream_t stream) {
  const float* x        = (const float*)d_in[0];
  const float* pre_h    = (const float*)d_in[1];
  const float* edge_attr= (const float*)d_in[2];
  const float* enc_w    = (const float*)d_in[3];
  const float* enc_b    = (const float*)d_in[4];
  const float* M_w      = (const float*)d_in[5];
  const float* M_b      = (const float*)d_in[6];
  const float* U_w      = (const float*)d_in[7];
  const float* U_b      = (const float*)d_in[8];
  const float* dec_w    = (const float*)d_in[9];
  const float* dec_b    = (const float*)d_in[10];
  const float* ter_w    = (const float*)d_in[11];
  const float* ter_b    = (const float*)d_in[12];
  const int*   edge_idx = (const int*)d_in[13];

  const int N = in_sizes[0];      // 50000
  const int E = in_sizes[2];      // 600000
  const size_t NH = (size_t)N * HD;

  float* out = (float*)d_out;
  float* h_out = out;             // [0, N*H)
  float* y_out = out + NH;        // [N*H, N*H+N)
  float* ter_out = out + NH + N;

  // ws layout (bf16 z/P/Q): zg | Pg | Qg | cursor(N) | row_ptr(N) | partials(64)
  //                         | hsum(128) | epack(E int2) | encf | Pf | Qf | Uf
  unsigned short* zg = (unsigned short*)d_ws;
  unsigned short* Pg = zg + NH;
  unsigned short* Qg = Pg + NH;
  int*   cursor   = (int*)(Qg + NH);
  int*   row_ptr  = cursor + N;
  int*   partials = row_ptr + N;
  float* hsum     = (float*)(partials + 64);
  int2*  epack    = (int2*)(hsum + HD);
  unsigned short* encf = (unsigned short*)(epack + E);
  unsigned short* Pf   = encf + 8 * 4 * 64 * 8;
  unsigned short* Qf   = Pf + 8 * 4 * 64 * 8;
  unsigned short* Uf   = Qf + 8 * 4 * 64 * 8;

  hipMemsetAsync(cursor, 0, (2 * (size_t)N + 64 + HD) * sizeof(int), stream);

  const int scan_blocks = (N + 1023) / 1024;  // 49
  const int eb = (E + 255) / 256;             // 2344

  k_frag<<<40, 256, 0, stream>>>(enc_w, M_w, U_w, encf, Pf, Qf, Uf);

  k_hist<<<eb, 256, 0, stream>>>(edge_idx, cursor, E);
  k_scan_block<<<scan_blocks, 256, 0, stream>>>(cursor, row_ptr, partials, N);
  k_scan_partials<<<1, 64, 0, stream>>>(partials, scan_blocks);
  k_scan_add<<<scan_blocks, 256, 0, stream>>>(row_ptr, partials, cursor, N);
  k_scatter<<<eb, 256, 0, stream>>>(edge_idx, edge_attr, cursor, epack, E);

  k_enc_pq<<<N / 16, 256, 0, stream>>>(x, pre_h, enc_w, enc_b, M_b,
                                       encf, Pf, Qf, zg, Pg, Qg);
  k_gather_update<<<(N + 31) / 32, 256, 0, stream>>>(
      zg, Pg, Qg, M_w + 256 * HD, row_ptr, cursor, epack, Uf,
      U_b, dec_w, dec_b, h_out, y_out, hsum, N);
  k_ter<<<1, 128, 0, stream>>>(hsum, ter_w, ter_b, ter_out, 1.0f / (float)N);
}